// Round 1
// 186.540 us; speedup vs baseline: 1.0405x; 1.0405x over previous
//
#include <hip/hip_runtime.h>
#include <hip/hip_bf16.h>

typedef __bf16 bf16_t;
typedef __bf16 bf16x8 __attribute__((ext_vector_type(8)));
typedef float f32x4 __attribute__((ext_vector_type(4)));

#define IN_DIM 21
#define HID 512
#define OUT_DIM 21
#define M_TILE 64
#define THREADS 1024  // 16 waves -> 1 block/CU (LDS-capped), 4 waves/SIMD

// XOR swizzle (element units): flips col bits 3..5 with row low bits.
// Row stride is 512 elems = 1024 B (bank-aligned); the XOR spreads each row's
// 16B chunks across the 8 bank-quads -> ds_read_b128 per-row pattern is
// conflict-free (2-way max, free per m136). Same mapping on write and read.
__device__ __forceinline__ int swz(int row, int col) {
    return col ^ ((row & 7) << 3);
}

// ---- prep: convert weights fp32 -> bf16 *fragment-major* layouts in ws ----
// B-fragment for 16x16x32 mfma: element (n = ntile*16 + (lane&15), k = k0 + (lane>>4)*8 + j)
// stored at frag_base + lane*8 + j  ->  wave load is contiguous 1 KB.
// W2f: [kstep(16)][ntile(32)][512]   W1f: [ntile(32)][512] (k>=21 zero)
// W3f: [kstep(16)][otile(2)][512]    (o>=21 zero)
__global__ void prep_kernel(const float* __restrict__ W1, const float* __restrict__ W2,
                            const float* __restrict__ W3,
                            bf16_t* __restrict__ W1f, bf16_t* __restrict__ W2f,
                            bf16_t* __restrict__ W3f) {
    int i = blockIdx.x * blockDim.x + threadIdx.x;
    int stride = gridDim.x * blockDim.x;
    const int NW2 = HID * HID;     // 262144
    const int NW1 = 32 * 512;      // 16384
    const int NW3 = 16 * 2 * 512;  // 16384
    for (; i < NW2 + NW1 + NW3; i += stride) {
        if (i < NW2) {
            int j = i & 7, lane = (i >> 3) & 63, ntile = (i >> 9) & 31, kstep = i >> 14;
            int n = ntile * 16 + (lane & 15);
            int k = kstep * 32 + (lane >> 4) * 8 + j;
            W2f[i] = (bf16_t)W2[n * HID + k];
        } else if (i < NW2 + NW1) {
            int t = i - NW2;
            int j = t & 7, lane = (t >> 3) & 63, ntile = t >> 9;
            int n = ntile * 16 + (lane & 15);
            int k = (lane >> 4) * 8 + j;
            W1f[t] = (k < IN_DIM) ? (bf16_t)W1[n * IN_DIM + k] : (bf16_t)0.0f;
        } else {
            int t = i - NW2 - NW1;
            int j = t & 7, lane = (t >> 3) & 63, ot = (t >> 9) & 1, kstep = t >> 10;
            int o = ot * 16 + (lane & 15);
            int k = kstep * 32 + (lane >> 4) * 8 + j;
            W3f[t] = (o < OUT_DIM) ? (bf16_t)W3[o * HID + k] : (bf16_t)0.0f;
        }
    }
}

// ---- fused MLP + loss ----
__global__ __launch_bounds__(THREADS, 4)  // 4 waves/EU min -> VGPR cap 128 (we only ever fit 1 block/CU)
void fused_kernel(const float* __restrict__ V, const float* __restrict__ gt,
                  const float* __restrict__ b1, const float* __restrict__ b2,
                  const float* __restrict__ b3,
                  const bf16_t* __restrict__ W1f, const bf16_t* __restrict__ W2f,
                  const bf16_t* __restrict__ W3f, float* __restrict__ accum) {
    __shared__ __align__(16) bf16_t vlds[M_TILE][40];   // stride 80 B = 20 banks: b128 reads 2-way max
    __shared__ __align__(16) bf16_t h1[M_TILE][HID];    // XOR-swizzled
    __shared__ __align__(16) bf16_t h2[M_TILE][HID];    // XOR-swizzled
    __shared__ float redbuf[32];

    const int tid  = threadIdx.x;
    const int wave = tid >> 6;       // 0..15
    const int lane = tid & 63;
    const int quad = lane >> 4;
    const int l16  = lane & 15;
    const long row0 = (long)blockIdx.x * M_TILE;

    // phase 0: velocities tile -> LDS bf16, k padded to 32 with zeros
    for (int idx = tid; idx < M_TILE * 32; idx += THREADS) {
        int r = idx >> 5, c = idx & 31;
        float v = (c < IN_DIM) ? V[(row0 + r) * IN_DIM + c] : 0.0f;
        vlds[r][c] = (bf16_t)v;
    }
    __syncthreads();

    // phase 1: h1 = relu(V @ W1^T + b1). Wave covers n in [wave*32, wave*32+32).
    {
        bf16x8 a[4];
        #pragma unroll
        for (int mt = 0; mt < 4; ++mt)
            a[mt] = *reinterpret_cast<const bf16x8*>(&vlds[mt * 16 + l16][quad * 8]);
        #pragma unroll
        for (int nt = 0; nt < 2; ++nt) {
            int ntile = wave * 2 + nt;
            int n = ntile * 16 + l16;
            bf16x8 b = *reinterpret_cast<const bf16x8*>(W1f + ntile * 512 + lane * 8);
            float bias = b1[n];
            #pragma unroll
            for (int mt = 0; mt < 4; ++mt) {
                f32x4 c = {0.0f, 0.0f, 0.0f, 0.0f};
                c = __builtin_amdgcn_mfma_f32_16x16x32_bf16(a[mt], b, c, 0, 0, 0);
                #pragma unroll
                for (int r = 0; r < 4; ++r) {
                    float v = c[r] + bias;
                    v = v > 0.0f ? v : 0.0f;
                    int m = mt * 16 + quad * 4 + r;
                    h1[m][swz(m, n)] = (bf16_t)v;
                }
            }
        }
    }
    __syncthreads();

    // phase 2: h2 = relu(h1 @ W2^T + b2). M=64, N=512 (32/wave), K=512.
    // Software-pipelined: depth-2 rotation for W2f global loads (L2 ~200-300cy),
    // depth-1 ping-pong for h1 ds_read_b128 (~120cy). All indices compile-time
    // under full unroll (rule #20).
    {
        f32x4 acc[4][2];
        #pragma unroll
        for (int mt = 0; mt < 4; ++mt)
            #pragma unroll
            for (int nt = 0; nt < 2; ++nt)
                acc[mt][nt] = (f32x4){0.0f, 0.0f, 0.0f, 0.0f};

        const bf16_t* w2p = W2f + (wave * 2) * 512 + lane * 8;  // kstep stride = 16384 elems

        bf16x8 b0buf[3], b1buf[3];
        bf16x8 ac[4], an[4];
        #pragma unroll
        for (int p = 0; p < 2; ++p) {
            b0buf[p] = *reinterpret_cast<const bf16x8*>(w2p + p * 16384);
            b1buf[p] = *reinterpret_cast<const bf16x8*>(w2p + p * 16384 + 512);
        }
        #pragma unroll
        for (int mt = 0; mt < 4; ++mt) {
            int rr = mt * 16 + l16;
            ac[mt] = *reinterpret_cast<const bf16x8*>(&h1[rr][swz(rr, quad * 8)]);
        }

        #pragma unroll
        for (int ks = 0; ks < 16; ++ks) {
            if (ks + 2 < 16) {  // prefetch b for ks+2 (depth 2)
                b0buf[(ks + 2) % 3] = *reinterpret_cast<const bf16x8*>(w2p + (ks + 2) * 16384);
                b1buf[(ks + 2) % 3] = *reinterpret_cast<const bf16x8*>(w2p + (ks + 2) * 16384 + 512);
            }
            if (ks + 1 < 16) {  // prefetch a for ks+1 (depth 1)
                #pragma unroll
                for (int mt = 0; mt < 4; ++mt) {
                    int rr = mt * 16 + l16;
                    an[mt] = *reinterpret_cast<const bf16x8*>(&h1[rr][swz(rr, (ks + 1) * 32 + quad * 8)]);
                }
            }
            #pragma unroll
            for (int mt = 0; mt < 4; ++mt) {
                acc[mt][0] = __builtin_amdgcn_mfma_f32_16x16x32_bf16(ac[mt], b0buf[ks % 3], acc[mt][0], 0, 0, 0);
                acc[mt][1] = __builtin_amdgcn_mfma_f32_16x16x32_bf16(ac[mt], b1buf[ks % 3], acc[mt][1], 0, 0, 0);
            }
            #pragma unroll
            for (int mt = 0; mt < 4; ++mt) ac[mt] = an[mt];
        }

        #pragma unroll
        for (int nt = 0; nt < 2; ++nt) {
            int n = wave * 32 + nt * 16 + l16;
            float bias = b2[n];
            #pragma unroll
            for (int mt = 0; mt < 4; ++mt) {
                #pragma unroll
                for (int r = 0; r < 4; ++r) {
                    float v = acc[mt][nt][r] + bias;
                    v = v > 0.0f ? v : 0.0f;
                    int m = mt * 16 + quad * 4 + r;
                    h2[m][swz(m, n)] = (bf16_t)v;
                }
            }
        }
    }
    __syncthreads();

    // phase 3: out = h2 @ W3^T + b3. 8 tile-jobs (4 m-tiles x 2 o-tiles) on waves 0..7.
    // gt/b3 loads hoisted above the K-loop; acc chain split into 2 independent halves.
    if (wave < 8) {
        const int mt = wave >> 1;
        const int ot = wave & 1;
        const int col = ot * 16 + l16;
        const bool colv = (col < OUT_DIM);

        float g[4];
        float bias3 = 0.0f;
        if (colv) {
            bias3 = b3[col];
            #pragma unroll
            for (int r = 0; r < 4; ++r) {
                long grow = row0 + mt * 16 + quad * 4 + r;
                g[r] = gt[grow * OUT_DIM + col];
            }
        }

        f32x4 acc3a = {0.0f, 0.0f, 0.0f, 0.0f};
        f32x4 acc3b = {0.0f, 0.0f, 0.0f, 0.0f};
        const int rr = mt * 16 + l16;
        #pragma unroll
        for (int ks = 0; ks < 16; ks += 2) {
            bf16x8 a0 = *reinterpret_cast<const bf16x8*>(&h2[rr][swz(rr, ks * 32 + quad * 8)]);
            bf16x8 a1 = *reinterpret_cast<const bf16x8*>(&h2[rr][swz(rr, (ks + 1) * 32 + quad * 8)]);
            bf16x8 bb0 = *reinterpret_cast<const bf16x8*>(W3f + (ks * 2 + ot) * 512 + lane * 8);
            bf16x8 bb1 = *reinterpret_cast<const bf16x8*>(W3f + ((ks + 1) * 2 + ot) * 512 + lane * 8);
            acc3a = __builtin_amdgcn_mfma_f32_16x16x32_bf16(a0, bb0, acc3a, 0, 0, 0);
            acc3b = __builtin_amdgcn_mfma_f32_16x16x32_bf16(a1, bb1, acc3b, 0, 0, 0);
        }

        float num = 0.0f, den = 0.0f;
        if (colv) {
            #pragma unroll
            for (int r = 0; r < 4; ++r) {
                float pred = acc3a[r] + acc3b[r] + bias3;
                if (g[r] > -5000.0f) {
                    float w = (floorf(pred * 2.0f) == floorf(g[r] * 2.0f)) ? 0.5f : 1.0f;
                    num += fabsf(pred * w - g[r] * w);
                    den += 1.0f;
                }
            }
        }
        #pragma unroll
        for (int off = 32; off > 0; off >>= 1) {
            num += __shfl_down(num, off);
            den += __shfl_down(den, off);
        }
        if (lane == 0) { redbuf[wave * 2] = num; redbuf[wave * 2 + 1] = den; }
    }
    __syncthreads();
    if (tid == 0) {
        float n8 = 0.0f, d8 = 0.0f;
        #pragma unroll
        for (int w = 0; w < 8; ++w) { n8 += redbuf[w * 2]; d8 += redbuf[w * 2 + 1]; }
        atomicAdd(accum, n8);
        atomicAdd(accum + 1, d8);
    }
}

__global__ void finalize_kernel(const float* __restrict__ accum, float* __restrict__ out) {
    if (threadIdx.x == 0) out[0] = accum[0] / accum[1];
}

extern "C" void kernel_launch(void* const* d_in, const int* in_sizes, int n_in,
                              void* d_out, int out_size, void* d_ws, size_t ws_size,
                              hipStream_t stream) {
    const float* V  = (const float*)d_in[0];
    const float* gt = (const float*)d_in[1];
    const float* W1 = (const float*)d_in[2];
    const float* b1 = (const float*)d_in[3];
    const float* W2 = (const float*)d_in[4];
    const float* b2 = (const float*)d_in[5];
    const float* W3 = (const float*)d_in[6];
    const float* b3 = (const float*)d_in[7];
    float* out = (float*)d_out;

    char* ws = (char*)d_ws;
    float* accum = (float*)ws;                                       // 2 floats
    bf16_t* W2f = (bf16_t*)(ws + 16);                                // 512 KB
    bf16_t* W1f = (bf16_t*)(ws + 16 + 512 * 512 * 2);                // 32 KB
    bf16_t* W3f = (bf16_t*)(ws + 16 + 512 * 512 * 2 + 32 * 512 * 2); // 32 KB

    int Brows = in_sizes[0] / IN_DIM;   // 131072
    int grid = Brows / M_TILE;          // 2048

    hipMemsetAsync(accum, 0, 2 * sizeof(float), stream);
    prep_kernel<<<576, 512, 0, stream>>>(W1, W2, W3, W1f, W2f, W3f);
    fused_kernel<<<grid, THREADS, 0, stream>>>(V, gt, b1, b2, b3, W1f, W2f, W3f, accum);
    finalize_kernel<<<1, 64, 0, stream>>>(accum, out);
}